// Round 3
// baseline (410.003 us; speedup 1.0000x reference)
//
#include <hip/hip_runtime.h>
#include <math.h>

#define IN_C 128
#define NEG_SLOPE 0.2f

typedef unsigned int uint_t;
typedef unsigned short ushort_t;
typedef _Float16 half8_t __attribute__((ext_vector_type(8)));
typedef _Float16 half4_t __attribute__((ext_vector_type(4)));
typedef float floatx4 __attribute__((ext_vector_type(4)));
typedef uint_t u32x2 __attribute__((ext_vector_type(2)));

// ---------- MFMA dual transform: outl = x@Wl (f16), outr = x@Wr (f16) ----------
#define XPAD 136
template <bool IN_HALF>
__global__ __launch_bounds__(256) void transform_mfma(
        const void* __restrict__ xin,
        const float* __restrict__ Wl,
        const float* __restrict__ Wr,
        _Float16* __restrict__ outl,
        _Float16* __restrict__ outr, int n) {
    __shared__ _Float16 xs[16 * XPAD + 8];
    const int tid  = threadIdx.x;
    const int wv   = tid >> 6;
    const int l    = tid & 63;
    const int lm   = l & 15;
    const int quad = l >> 4;
    const int kb   = quad * 8;

    const float* Wsel = (wv < 2) ? Wl : Wr;
    _Float16*    osel = (wv < 2) ? outl : outr;
    const int nbase = (wv & 1) * 64;
    half8_t bw[4][4];
#pragma unroll
    for (int t = 0; t < 4; ++t) {
        const int ncol = nbase + t * 16 + lm;
#pragma unroll
        for (int K = 0; K < 4; ++K) {
            const int k0 = K * 32 + kb;
            half8_t h;
#pragma unroll
            for (int j = 0; j < 8; ++j)
                h[j] = (_Float16)Wsel[(size_t)(k0 + j) * IN_C + ncol];
            bw[t][K] = h;
        }
    }

    const int nStrips = (n + 15) >> 4;
    for (int s = blockIdx.x; s < nStrips; s += gridDim.x) {
        const int row0 = s * 16;
        __syncthreads();
        {
            const int srow = tid >> 4;
            const int scol = (tid & 15) * 8;
            const int grow = row0 + srow;
            half8_t h;
#pragma unroll
            for (int j = 0; j < 8; ++j) h[j] = (_Float16)0.f;
            if (grow < n) {
                if constexpr (IN_HALF) {
                    h = *(const half8_t*)&((const _Float16*)xin)[(size_t)grow * IN_C + scol];
                } else {
                    const float4 v0 = *(const float4*)&((const float*)xin)[(size_t)grow * IN_C + scol];
                    const float4 v1 = *(const float4*)&((const float*)xin)[(size_t)grow * IN_C + scol + 4];
                    h[0] = (_Float16)v0.x; h[1] = (_Float16)v0.y;
                    h[2] = (_Float16)v0.z; h[3] = (_Float16)v0.w;
                    h[4] = (_Float16)v1.x; h[5] = (_Float16)v1.y;
                    h[6] = (_Float16)v1.z; h[7] = (_Float16)v1.w;
                }
            }
            *(half8_t*)&xs[srow * XPAD + scol] = h;
        }
        __syncthreads();
        half8_t af[4];
#pragma unroll
        for (int K = 0; K < 4; ++K)
            af[K] = *(half8_t*)&xs[lm * XPAD + K * 32 + kb];
        floatx4 acc[4];
#pragma unroll
        for (int t = 0; t < 4; ++t) acc[t] = (floatx4){0.f, 0.f, 0.f, 0.f};
#pragma unroll
        for (int t = 0; t < 4; ++t)
#pragma unroll
            for (int K = 0; K < 4; ++K)
                acc[t] = __builtin_amdgcn_mfma_f32_16x16x32_f16(af[K], bw[t][K], acc[t], 0, 0, 0);
#pragma unroll
        for (int t = 0; t < 4; ++t) {
            const int col = nbase + t * 16 + lm;
#pragma unroll
            for (int r = 0; r < 4; ++r) {
                const int row = row0 + quad * 4 + r;
                if (row < n) osel[(size_t)row * IN_C + col] = (_Float16)acc[t][r];
            }
        }
    }
}

// ---------- CSR build (unchanged) ----------
__global__ void hist_kernel(const int* __restrict__ dst, int* __restrict__ cnt, int E) {
    int e = blockIdx.x * blockDim.x + threadIdx.x;
    if (e < E) atomicAdd(&cnt[dst[e]], 1);
}

__global__ void scan_block_sums(const int* __restrict__ cnt, int* __restrict__ part, int n) {
    __shared__ int sdata[256];
    int t = threadIdx.x;
    int i = blockIdx.x * 256 + t;
    sdata[t] = (i < n) ? cnt[i] : 0;
    __syncthreads();
    for (int o = 128; o >= 1; o >>= 1) {
        if (t < o) sdata[t] += sdata[t + o];
        __syncthreads();
    }
    if (t == 0) part[blockIdx.x] = sdata[0];
}

__global__ void scan_part_excl(int* __restrict__ part, int nb) {  // single block
    __shared__ int buf[1024];
    int t = threadIdx.x;
    int v = (t < nb) ? part[t] : 0;
    buf[t] = v;
    __syncthreads();
    for (int o = 1; o < 1024; o <<= 1) {
        int a = (t >= o) ? buf[t - o] : 0;
        __syncthreads();
        buf[t] += a;
        __syncthreads();
    }
    if (t < nb) part[t] = buf[t] - v;   // exclusive
}

__global__ void scan_final(const int* __restrict__ cnt, const int* __restrict__ part,
                           int* __restrict__ rowptr, int* __restrict__ cursor, int n) {
    __shared__ int buf[256];
    int t = threadIdx.x;
    int i = blockIdx.x * 256 + t;
    int v = (i < n) ? cnt[i] : 0;
    buf[t] = v;
    __syncthreads();
    for (int o = 1; o < 256; o <<= 1) {
        int a = (t >= o) ? buf[t - o] : 0;
        __syncthreads();
        buf[t] += a;
        __syncthreads();
    }
    int excl = part[blockIdx.x] + buf[t] - v;
    if (i < n) { rowptr[i] = excl; cursor[i] = excl; }
    if (i == n - 1) rowptr[n] = excl + v;
}

__global__ void scatter_csr(const int* __restrict__ src,
                            const int* __restrict__ dst,
                            int* __restrict__ cursor,
                            ushort_t* __restrict__ gsrc, int E) {
    int e = blockIdx.x * blockDim.x + threadIdx.x;
    if (e >= E) return;
    int pos = atomicAdd(&cursor[dst[e]], 1);
    gsrc[pos] = (ushort_t)src[e];
}

// ---------- fused node kernel: one dst per wave, 16-edge MFMA tiles ----------
// Scores:  A = lrelu(xl[src]+xr[d]) tile (gather layout IS the A-frag of
//          16x16x32_f16), B = head-masked att  ->  4 MFMAs = 16 edges x 4 heads.
//          A and B both register-slot-ordered by channel -> k-order cancels.
// Softmax: C-layout (lane = head col, 4 edge-rows/lane), online w/ defer-max.
// Aggregation: D[c] += xl^T @ alpha via 16x16x16f16. A (xl^T) comes from a
//          pair-transposed LDS tile (plain ds_write_b32 / ds_read_b128 +
//          v_perm parity select); B = lane's OWN alphas. Both operands are
//          register-slot-ordered by edge j = grp*4+j -> immune to any
//          slot->k permutation convention (unlike the tr_b16 path).
// LDS layout: elem(ch, e) = (ch>>1)*40 + e*2 + (ch&1)   [pair-major, pitch 40]
template <int LAYER>   // 1: 4 heads + ELU + f16 out; 2: 1 head, f32 out
__global__ __launch_bounds__(256) void node_fused(
        const _Float16* __restrict__ xl,
        const _Float16* __restrict__ xr,
        const float* __restrict__ att,
        const int* __restrict__ rowptr,
        const ushort_t* __restrict__ gsrc,
        const float* __restrict__ bias,
        void* __restrict__ outp, int N) {
    __shared__ uint_t ldsu[4][1280];   // 5120 B per wave (64 ch-pairs x pitch 20 u32)
    const int tid = threadIdx.x;
    const int wv  = tid >> 6;
    const int l   = tid & 63;
    const int col = l & 15;     // MFMA col slot (edge for gather, head for C)
    const int grp = l >> 4;     // row-group
    const int d   = blockIdx.x * 4 + wv;
    if (d >= N) return;
    uint_t* ldsw = ldsu[wv];
    const int beg = rowptr[d], end = rowptr[d + 1];

    // xr fragment matching score-A k-layout: 8 ch at K*32 + grp*8
    half8_t xrv[4];
#pragma unroll
    for (int K = 0; K < 4; ++K)
        xrv[K] = *(const half8_t*)&xr[(size_t)d * IN_C + K * 32 + grp * 8];

    // att B-fragments (f16); layer1: col gets head col&3 (replicated x4)
    half8_t batt[4];
#pragma unroll
    for (int K = 0; K < 4; ++K) {
        const float* ap = &att[K * 32 + grp * 8];
        const bool keep = (LAYER == 2) || ((col & 3) == K);
        half8_t h;
#pragma unroll
        for (int j = 0; j < 8; ++j)
            h[j] = keep ? (_Float16)ap[j] : (_Float16)0.f;
        batt[K] = h;
    }

    // byte-selector for parity extraction (per-lane v_perm selector)
    const uint_t psel = (col & 1) ? 0x07060302u : 0x05040100u;

    floatx4 D[8];
#pragma unroll
    for (int c = 0; c < 8; ++c) D[c] = (floatx4){0.f, 0.f, 0.f, 0.f};
    float m = -1e30f, ls = 0.f;

    for (int c0 = beg; c0 < end; c0 += 16) {
        const int eidx = min(c0 + col, end - 1);
        const int sA   = (int)gsrc[eidx];
        const uint4* xrow = (const uint4*)(xl + (size_t)sA * IN_C + grp * 8);
        uint4 xq[4];
#pragma unroll
        for (int K = 0; K < 4; ++K) xq[K] = xrow[K * 4];
        // stage xl tile pair-transposed: dword t of xq[K] = channels
        // (K*32+grp*8+2t, +2t+1) of edge col -> row (K*16+grp*4+t), slot col
#pragma unroll
        for (int K = 0; K < 4; ++K) {
            ldsw[(K * 16 + grp * 4 + 0) * 20 + col] = xq[K].x;
            ldsw[(K * 16 + grp * 4 + 1) * 20 + col] = xq[K].y;
            ldsw[(K * 16 + grp * 4 + 2) * 20 + col] = xq[K].z;
            ldsw[(K * 16 + grp * 4 + 3) * 20 + col] = xq[K].w;
        }
        // packed-f16 leaky-relu + score MFMAs
        floatx4 sc = (floatx4){0.f, 0.f, 0.f, 0.f};
#pragma unroll
        for (int K = 0; K < 4; ++K) {
            half8_t t = __builtin_bit_cast(half8_t, xq[K]) + xrv[K];
            uint4 tu = __builtin_bit_cast(uint4, t);
            tu.x &= 0x7fff7fffu; tu.y &= 0x7fff7fffu;
            tu.z &= 0x7fff7fffu; tu.w &= 0x7fff7fffu;
            half8_t lr = t * (_Float16)0.6f + __builtin_bit_cast(half8_t, tu) * (_Float16)0.4f;
            sc = __builtin_amdgcn_mfma_f32_16x16x32_f16(lr, batt[K], sc, 0, 0, 0);
        }
        // tail mask (rows beyond end)
        const int rbase = c0 + grp * 4;
#pragma unroll
        for (int r = 0; r < 4; ++r)
            if (rbase + r >= end) sc[r] = -1e30f;
        // online softmax with defer-max (THR=4)
        float bm = fmaxf(fmaxf(sc[0], sc[1]), fmaxf(sc[2], sc[3]));
        bm = fmaxf(bm, __shfl_xor(bm, 16, 64));
        bm = fmaxf(bm, __shfl_xor(bm, 32, 64));
        if (c0 == beg) {
            m = bm;
        } else if (__any(bm > m + 4.f)) {
            float nm = fmaxf(m, bm);
            float fc = __expf(m - nm);
            ls *= fc;
#pragma unroll
            for (int c = 0; c < 8; ++c) {
                D[c][0] *= fc; D[c][1] *= fc; D[c][2] *= fc; D[c][3] *= fc;
            }
            m = nm;
        }
        float a0 = __expf(sc[0] - m), a1 = __expf(sc[1] - m);
        float a2 = __expf(sc[2] - m), a3 = __expf(sc[3] - m);
        half4_t ab;
        ab[0] = (_Float16)a0; ab[1] = (_Float16)a1;
        ab[2] = (_Float16)a2; ab[3] = (_Float16)a3;
        // numerator/denominator consistent: sum the f16-rounded alphas
        ls += ((float)ab[0] + (float)ab[1]) + ((float)ab[2] + (float)ab[3]);
        // aggregation: D[c] += xl_tile^T @ alpha
        // A-frag slot j = edge grp*4+j (parity-selected via v_perm);
        // B-frag slot j = alpha of edge grp*4+j  -> slot orders match.
#pragma unroll
        for (int c = 0; c < 8; ++c) {
            uint4 q = *(const uint4*)&ldsw[(c * 8 + (col >> 1)) * 20 + grp * 4];
            u32x2 s;
            s[0] = __builtin_amdgcn_perm(q.y, q.x, psel);
            s[1] = __builtin_amdgcn_perm(q.w, q.z, psel);
            D[c] = __builtin_amdgcn_mfma_f32_16x16x16f16(
                __builtin_bit_cast(half4_t, s), ab, D[c], 0, 0, 0);
        }
    }

    // denominator: D summed all 16 edges (K=16) but each lane's ls only its
    // own grp's 4 rows -> reduce across the 4 row-groups
    ls += __shfl_xor(ls, 16, 64);
    ls += __shfl_xor(ls, 32, 64);

    // epilogue: cols 0..7 cover the 8 16-channel chunks (head = col&3 for L1)
    if (col < 8) {
        const int c = (LAYER == 1) ? (2 * (col & 3) + ((col >> 2) & 1)) : col;
        floatx4 Dv = D[0];
#pragma unroll
        for (int cc = 1; cc < 8; ++cc)
            if (c == cc) Dv = D[cc];
        const float inv = (ls > 0.f) ? 1.f / ls : 0.f;
        const int chb = c * 16 + grp * 4;
        const float4 bv = *(const float4*)&bias[chb];
        float o0 = Dv[0] * inv + bv.x;
        float o1 = Dv[1] * inv + bv.y;
        float o2 = Dv[2] * inv + bv.z;
        float o3 = Dv[3] * inv + bv.w;
        if (LAYER == 1) {
            // ELU via exp(x)-1 (absolute err ~1e-7, well under tolerance)
            o0 = (o0 > 0.f) ? o0 : __expf(o0) - 1.f;
            o1 = (o1 > 0.f) ? o1 : __expf(o1) - 1.f;
            o2 = (o2 > 0.f) ? o2 : __expf(o2) - 1.f;
            o3 = (o3 > 0.f) ? o3 : __expf(o3) - 1.f;
            half4_t h;
            h[0] = (_Float16)o0; h[1] = (_Float16)o1;
            h[2] = (_Float16)o2; h[3] = (_Float16)o3;
            *(half4_t*)&((_Float16*)outp)[(size_t)d * IN_C + chb] = h;
        } else {
            float4 o;
            o.x = o0; o.y = o1; o.z = o2; o.w = o3;
            *(float4*)&((float*)outp)[(size_t)d * IN_C + chb] = o;
        }
    }
}

extern "C" void kernel_launch(void* const* d_in, const int* in_sizes, int n_in,
                              void* d_out, int out_size, void* d_ws, size_t ws_size,
                              hipStream_t stream) {
    const float* x    = (const float*)d_in[0];
    const int*   ei   = (const int*)d_in[1];
    const float* W1l  = (const float*)d_in[2];
    const float* W1r  = (const float*)d_in[3];
    const float* att1 = (const float*)d_in[4];
    const float* b1   = (const float*)d_in[5];
    const float* W2l  = (const float*)d_in[6];
    const float* W2r  = (const float*)d_in[7];
    const float* att2 = (const float*)d_in[8];
    const float* b2   = (const float*)d_in[9];

    const int N = in_sizes[0] / IN_C;
    const int E = in_sizes[1] / 2;
    const int* src = ei;
    const int* dst = ei + E;

    // workspace layout (all f16 feature buffers)
    float* ws = (float*)d_ws;
    size_t o = 0;
    _Float16* xlh = (_Float16*)(ws + o); o += (size_t)N * IN_C / 2;  // x@Wl / h@W2l
    _Float16* xrh = (_Float16*)(ws + o); o += (size_t)N * IN_C / 2;  // x@Wr / h@W2r
    _Float16* hb  = (_Float16*)(ws + o); o += (size_t)N * IN_C / 2;  // layer1 out (post-ELU)
    int* iws    = (int*)(ws + o);
    int* rowptr = iws;                    // N+1
    int* cnt    = iws + (N + 1);          // N
    int* cursor = iws + (N + 1) + N;      // N   (seeded by scan_final)
    int* part   = iws + (N + 1) + 2 * N;  // <=1024 block partials
    ushort_t* gsrc = (ushort_t*)(iws + (N + 1) + 2 * N + 1024);  // E (CSR src ids)

    hipMemsetAsync(cnt, 0, (size_t)N * 4, stream);

    const int B = 256;
    const int nb = (N + 255) / 256;
    // ---- CSR by dst (shared by both layers) ----
    hist_kernel<<<(E + B - 1) / B, B, 0, stream>>>(dst, cnt, E);
    scan_block_sums<<<nb, 256, 0, stream>>>(cnt, part, N);
    scan_part_excl<<<1, 1024, 0, stream>>>(part, nb);
    scan_final<<<nb, 256, 0, stream>>>(cnt, part, rowptr, cursor, N);
    scatter_csr<<<(E + B - 1) / B, B, 0, stream>>>(src, dst, cursor, gsrc, E);

    // ---- layer 1 ----
    transform_mfma<false><<<512, 256, 0, stream>>>(x, W1l, W1r, xlh, xrh, N);
    node_fused<1><<<(N + 3) / 4, 256, 0, stream>>>(xlh, xrh, att1, rowptr, gsrc, b1, hb, N);

    // ---- layer 2 ----
    transform_mfma<true><<<512, 256, 0, stream>>>(hb, W2l, W2r, xlh, xrh, N);
    node_fused<2><<<(N + 3) / 4, 256, 0, stream>>>(xlh, xrh, att2, rowptr, gsrc, b2, d_out, N);
}

// Round 4
// 302.380 us; speedup vs baseline: 1.3559x; 1.3559x over previous
//
#include <hip/hip_runtime.h>
#include <math.h>

#define IN_C 128
#define NEG_SLOPE 0.2f

typedef unsigned int uint_t;
typedef unsigned short ushort_t;
typedef _Float16 half8_t __attribute__((ext_vector_type(8)));
typedef _Float16 half4_t __attribute__((ext_vector_type(4)));
typedef _Float16 half2_t __attribute__((ext_vector_type(2)));
typedef float floatx4 __attribute__((ext_vector_type(4)));

// f16 pair dot with f32 accumulate (v_dot2_f32_f16); safe fallback
__device__ __forceinline__ float fdot2f(half2_t a, half2_t b, float c) {
#if __has_builtin(__builtin_amdgcn_fdot2)
    return __builtin_amdgcn_fdot2(a, b, c, false);
#else
    return fmaf((float)a[1], (float)b[1], fmaf((float)a[0], (float)b[0], c));
#endif
}
#define H2(v, i) ((half2_t){(v)[2 * (i)], (v)[2 * (i) + 1]})

// ---------- MFMA dual transform: outl = x@Wl (f16), outr = x@Wr (f16) ----------
#define XPAD 136
template <bool IN_HALF>
__global__ __launch_bounds__(256) void transform_mfma(
        const void* __restrict__ xin,
        const float* __restrict__ Wl,
        const float* __restrict__ Wr,
        _Float16* __restrict__ outl,
        _Float16* __restrict__ outr, int n) {
    __shared__ _Float16 xs[16 * XPAD + 8];
    const int tid  = threadIdx.x;
    const int wv   = tid >> 6;
    const int l    = tid & 63;
    const int lm   = l & 15;
    const int quad = l >> 4;
    const int kb   = quad * 8;

    const float* Wsel = (wv < 2) ? Wl : Wr;
    _Float16*    osel = (wv < 2) ? outl : outr;
    const int nbase = (wv & 1) * 64;
    half8_t bw[4][4];
#pragma unroll
    for (int t = 0; t < 4; ++t) {
        const int ncol = nbase + t * 16 + lm;
#pragma unroll
        for (int K = 0; K < 4; ++K) {
            const int k0 = K * 32 + kb;
            half8_t h;
#pragma unroll
            for (int j = 0; j < 8; ++j)
                h[j] = (_Float16)Wsel[(size_t)(k0 + j) * IN_C + ncol];
            bw[t][K] = h;
        }
    }

    const int nStrips = (n + 15) >> 4;
    for (int s = blockIdx.x; s < nStrips; s += gridDim.x) {
        const int row0 = s * 16;
        __syncthreads();
        {
            const int srow = tid >> 4;
            const int scol = (tid & 15) * 8;
            const int grow = row0 + srow;
            half8_t h;
#pragma unroll
            for (int j = 0; j < 8; ++j) h[j] = (_Float16)0.f;
            if (grow < n) {
                if constexpr (IN_HALF) {
                    h = *(const half8_t*)&((const _Float16*)xin)[(size_t)grow * IN_C + scol];
                } else {
                    const float4 v0 = *(const float4*)&((const float*)xin)[(size_t)grow * IN_C + scol];
                    const float4 v1 = *(const float4*)&((const float*)xin)[(size_t)grow * IN_C + scol + 4];
                    h[0] = (_Float16)v0.x; h[1] = (_Float16)v0.y;
                    h[2] = (_Float16)v0.z; h[3] = (_Float16)v0.w;
                    h[4] = (_Float16)v1.x; h[5] = (_Float16)v1.y;
                    h[6] = (_Float16)v1.z; h[7] = (_Float16)v1.w;
                }
            }
            *(half8_t*)&xs[srow * XPAD + scol] = h;
        }
        __syncthreads();
        half8_t af[4];
#pragma unroll
        for (int K = 0; K < 4; ++K)
            af[K] = *(half8_t*)&xs[lm * XPAD + K * 32 + kb];
        floatx4 acc[4];
#pragma unroll
        for (int t = 0; t < 4; ++t) acc[t] = (floatx4){0.f, 0.f, 0.f, 0.f};
#pragma unroll
        for (int t = 0; t < 4; ++t)
#pragma unroll
            for (int K = 0; K < 4; ++K)
                acc[t] = __builtin_amdgcn_mfma_f32_16x16x32_f16(af[K], bw[t][K], acc[t], 0, 0, 0);
#pragma unroll
        for (int t = 0; t < 4; ++t) {
            const int col = nbase + t * 16 + lm;
#pragma unroll
            for (int r = 0; r < 4; ++r) {
                const int row = row0 + quad * 4 + r;
                if (row < n) osel[(size_t)row * IN_C + col] = (_Float16)acc[t][r];
            }
        }
    }
}

// ---------- CSR build (unchanged) ----------
__global__ void hist_kernel(const int* __restrict__ dst, int* __restrict__ cnt, int E) {
    int e = blockIdx.x * blockDim.x + threadIdx.x;
    if (e < E) atomicAdd(&cnt[dst[e]], 1);
}

__global__ void scan_block_sums(const int* __restrict__ cnt, int* __restrict__ part, int n) {
    __shared__ int sdata[256];
    int t = threadIdx.x;
    int i = blockIdx.x * 256 + t;
    sdata[t] = (i < n) ? cnt[i] : 0;
    __syncthreads();
    for (int o = 128; o >= 1; o >>= 1) {
        if (t < o) sdata[t] += sdata[t + o];
        __syncthreads();
    }
    if (t == 0) part[blockIdx.x] = sdata[0];
}

__global__ void scan_part_excl(int* __restrict__ part, int nb) {  // single block
    __shared__ int buf[1024];
    int t = threadIdx.x;
    int v = (t < nb) ? part[t] : 0;
    buf[t] = v;
    __syncthreads();
    for (int o = 1; o < 1024; o <<= 1) {
        int a = (t >= o) ? buf[t - o] : 0;
        __syncthreads();
        buf[t] += a;
        __syncthreads();
    }
    if (t < nb) part[t] = buf[t] - v;   // exclusive
}

__global__ void scan_final(const int* __restrict__ cnt, const int* __restrict__ part,
                           int* __restrict__ rowptr, int* __restrict__ cursor, int n) {
    __shared__ int buf[256];
    int t = threadIdx.x;
    int i = blockIdx.x * 256 + t;
    int v = (i < n) ? cnt[i] : 0;
    buf[t] = v;
    __syncthreads();
    for (int o = 1; o < 256; o <<= 1) {
        int a = (t >= o) ? buf[t - o] : 0;
        __syncthreads();
        buf[t] += a;
        __syncthreads();
    }
    int excl = part[blockIdx.x] + buf[t] - v;
    if (i < n) { rowptr[i] = excl; cursor[i] = excl; }
    if (i == n - 1) rowptr[n] = excl + v;
}

__global__ void scatter_csr(const int* __restrict__ src,
                            const int* __restrict__ dst,
                            int* __restrict__ cursor,
                            ushort_t* __restrict__ gsrc, int E) {
    int e = blockIdx.x * blockDim.x + threadIdx.x;
    if (e >= E) return;
    int pos = atomicAdd(&cursor[dst[e]], 1);
    gsrc[pos] = (ushort_t)src[e];
}

// ---------- fused node kernels: scalar structure (proven), packed-f16 math ----
// layer 1: 4 heads x 32ch; head of lane = q>>2; reduce within 4 lanes.
__global__ __launch_bounds__(256) void node_fused1(
        const _Float16* __restrict__ xlb,
        const _Float16* __restrict__ xr,
        const float* __restrict__ att,
        const int* __restrict__ rowptr,
        const ushort_t* __restrict__ gsrc,
        const float* __restrict__ b,
        _Float16* __restrict__ hout, int N) {
    const int wv = threadIdx.x >> 6;
    const int l  = threadIdx.x & 63;
    const int g  = l >> 4, q = l & 15;
    const int d  = blockIdx.x * 4 + wv;
    if (d >= N) return;
    const int beg = rowptr[d], end = rowptr[d + 1];
    const int cb = q * 8;
    const half8_t xrv = *(const half8_t*)&xr[(size_t)d * IN_C + cb];
    const float4 aa0 = *(const float4*)&att[cb];
    const float4 aa1 = *(const float4*)&att[cb + 4];
    const float af[8] = {aa0.x, aa0.y, aa0.z, aa0.w, aa1.x, aa1.y, aa1.z, aa1.w};
    half8_t a6, a4;
#pragma unroll
    for (int j = 0; j < 8; ++j) {
        a6[j] = (_Float16)(0.6f * af[j]);
        a4[j] = (_Float16)(0.4f * af[j]);
    }
    float m = -1e30f, ls = 0.f;
    float acc[8] = {0.f, 0.f, 0.f, 0.f, 0.f, 0.f, 0.f, 0.f};
    for (int c0 = beg; c0 < end; c0 += 16) {
        int sA[4];
#pragma unroll
        for (int u = 0; u < 4; ++u)
            sA[u] = (int)gsrc[min(c0 + 4 * u + g, end - 1)];
        half8_t xv[4];
#pragma unroll
        for (int u = 0; u < 4; ++u)
            xv[u] = *(const half8_t*)&xlb[(size_t)sA[u] * IN_C + cb];
        float f[4];
#pragma unroll
        for (int u = 0; u < 4; ++u) {
            half8_t tv = xv[u] + xrv;                 // 4x v_pk_add_f16
            uint4 tu = __builtin_bit_cast(uint4, tv);
            tu.x &= 0x7fff7fffu; tu.y &= 0x7fff7fffu;
            tu.z &= 0x7fff7fffu; tu.w &= 0x7fff7fffu; // |t| packed
            half8_t av = __builtin_bit_cast(half8_t, tu);
            float p = 0.f;
#pragma unroll
            for (int j = 0; j < 4; ++j) p = fdot2f(H2(tv, j), H2(a6, j), p);
#pragma unroll
            for (int j = 0; j < 4; ++j) p = fdot2f(H2(av, j), H2(a4, j), p);
            p += __shfl_xor(p, 1, 64);
            p += __shfl_xor(p, 2, 64);
            f[u] = (c0 + 4 * u + g < end) ? p : -1e30f;
        }
        float bm = fmaxf(fmaxf(f[0], f[1]), fmaxf(f[2], f[3]));
        float nm = fmaxf(m, bm);
        float fc = __expf(m - nm);
        ls *= fc;
#pragma unroll
        for (int j = 0; j < 8; ++j) acc[j] *= fc;
#pragma unroll
        for (int u = 0; u < 4; ++u) {
            float wgt = __expf(f[u] - nm);
            ls += wgt;
#pragma unroll
            for (int j = 0; j < 8; ++j)               // v_fma_mix: f16 * f32 + f32
                acc[j] = fmaf((float)xv[u][j], wgt, acc[j]);
        }
        m = nm;
    }
    // merge 4 groups (xor 16/32 partners share q -> same head)
#pragma unroll
    for (int o = 16; o <= 32; o <<= 1) {
        float mo = __shfl_xor(m, o, 64);
        float lo = __shfl_xor(ls, o, 64);
        float ao[8];
#pragma unroll
        for (int j = 0; j < 8; ++j) ao[j] = __shfl_xor(acc[j], o, 64);
        float nm = fmaxf(m, mo);
        float fs = __expf(m - nm), fo = __expf(mo - nm);
        ls = ls * fs + lo * fo;
#pragma unroll
        for (int j = 0; j < 8; ++j) acc[j] = acc[j] * fs + ao[j] * fo;
        m = nm;
    }
    if (g == 0) {
        float inv = (ls > 0.f) ? 1.f / ls : 0.f;
        const float4 b0 = *(const float4*)&b[cb];
        const float4 b1 = *(const float4*)&b[cb + 4];
        const float bf[8] = {b0.x, b0.y, b0.z, b0.w, b1.x, b1.y, b1.z, b1.w};
        half8_t h;
#pragma unroll
        for (int j = 0; j < 8; ++j) {
            float o = acc[j] * inv + bf[j];
            o = (o > 0.f) ? o : __expf(o) - 1.f;      // ELU
            h[j] = (_Float16)o;
        }
        *(half8_t*)&hout[(size_t)d * IN_C + cb] = h;
    }
}

// layer 2: single head x 128ch; reduce within all 16 lanes of the group.
__global__ __launch_bounds__(256) void node_fused2(
        const _Float16* __restrict__ xlb,
        const _Float16* __restrict__ xr,
        const float* __restrict__ att,
        const int* __restrict__ rowptr,
        const ushort_t* __restrict__ gsrc,
        const float* __restrict__ b,
        float* __restrict__ out, int N) {
    const int wv = threadIdx.x >> 6;
    const int l  = threadIdx.x & 63;
    const int g  = l >> 4, q = l & 15;
    const int d  = blockIdx.x * 4 + wv;
    if (d >= N) return;
    const int beg = rowptr[d], end = rowptr[d + 1];
    const int cb = q * 8;
    const half8_t xrv = *(const half8_t*)&xr[(size_t)d * IN_C + cb];
    const float4 aa0 = *(const float4*)&att[cb];
    const float4 aa1 = *(const float4*)&att[cb + 4];
    const float af[8] = {aa0.x, aa0.y, aa0.z, aa0.w, aa1.x, aa1.y, aa1.z, aa1.w};
    half8_t a6, a4;
#pragma unroll
    for (int j = 0; j < 8; ++j) {
        a6[j] = (_Float16)(0.6f * af[j]);
        a4[j] = (_Float16)(0.4f * af[j]);
    }
    float m = -1e30f, ls = 0.f;
    float acc[8] = {0.f, 0.f, 0.f, 0.f, 0.f, 0.f, 0.f, 0.f};
    for (int c0 = beg; c0 < end; c0 += 16) {
        int sA[4];
#pragma unroll
        for (int u = 0; u < 4; ++u)
            sA[u] = (int)gsrc[min(c0 + 4 * u + g, end - 1)];
        half8_t xv[4];
#pragma unroll
        for (int u = 0; u < 4; ++u)
            xv[u] = *(const half8_t*)&xlb[(size_t)sA[u] * IN_C + cb];
        float f[4];
#pragma unroll
        for (int u = 0; u < 4; ++u) {
            half8_t tv = xv[u] + xrv;
            uint4 tu = __builtin_bit_cast(uint4, tv);
            tu.x &= 0x7fff7fffu; tu.y &= 0x7fff7fffu;
            tu.z &= 0x7fff7fffu; tu.w &= 0x7fff7fffu;
            half8_t av = __builtin_bit_cast(half8_t, tu);
            float p = 0.f;
#pragma unroll
            for (int j = 0; j < 4; ++j) p = fdot2f(H2(tv, j), H2(a6, j), p);
#pragma unroll
            for (int j = 0; j < 4; ++j) p = fdot2f(H2(av, j), H2(a4, j), p);
            p += __shfl_xor(p, 1, 64);
            p += __shfl_xor(p, 2, 64);
            p += __shfl_xor(p, 4, 64);
            p += __shfl_xor(p, 8, 64);
            f[u] = (c0 + 4 * u + g < end) ? p : -1e30f;
        }
        float bm = fmaxf(fmaxf(f[0], f[1]), fmaxf(f[2], f[3]));
        float nm = fmaxf(m, bm);
        float fc = __expf(m - nm);
        ls *= fc;
#pragma unroll
        for (int j = 0; j < 8; ++j) acc[j] *= fc;
#pragma unroll
        for (int u = 0; u < 4; ++u) {
            float wgt = __expf(f[u] - nm);
            ls += wgt;
#pragma unroll
            for (int j = 0; j < 8; ++j)
                acc[j] = fmaf((float)xv[u][j], wgt, acc[j]);
        }
        m = nm;
    }
#pragma unroll
    for (int o = 16; o <= 32; o <<= 1) {
        float mo = __shfl_xor(m, o, 64);
        float lo = __shfl_xor(ls, o, 64);
        float ao[8];
#pragma unroll
        for (int j = 0; j < 8; ++j) ao[j] = __shfl_xor(acc[j], o, 64);
        float nm = fmaxf(m, mo);
        float fs = __expf(m - nm), fo = __expf(mo - nm);
        ls = ls * fs + lo * fo;
#pragma unroll
        for (int j = 0; j < 8; ++j) acc[j] = acc[j] * fs + ao[j] * fo;
        m = nm;
    }
    if (g == 0) {
        float inv = (ls > 0.f) ? 1.f / ls : 0.f;
        const float4 b0 = *(const float4*)&b[cb];
        const float4 b1 = *(const float4*)&b[cb + 4];
        float4 o1, o2;
        o1.x = acc[0] * inv + b0.x; o1.y = acc[1] * inv + b0.y;
        o1.z = acc[2] * inv + b0.z; o1.w = acc[3] * inv + b0.w;
        o2.x = acc[4] * inv + b1.x; o2.y = acc[5] * inv + b1.y;
        o2.z = acc[6] * inv + b1.z; o2.w = acc[7] * inv + b1.w;
        *(float4*)&out[(size_t)d * IN_C + cb]     = o1;
        *(float4*)&out[(size_t)d * IN_C + cb + 4] = o2;
    }
}

extern "C" void kernel_launch(void* const* d_in, const int* in_sizes, int n_in,
                              void* d_out, int out_size, void* d_ws, size_t ws_size,
                              hipStream_t stream) {
    const float* x    = (const float*)d_in[0];
    const int*   ei   = (const int*)d_in[1];
    const float* W1l  = (const float*)d_in[2];
    const float* W1r  = (const float*)d_in[3];
    const float* att1 = (const float*)d_in[4];
    const float* b1   = (const float*)d_in[5];
    const float* W2l  = (const float*)d_in[6];
    const float* W2r  = (const float*)d_in[7];
    const float* att2 = (const float*)d_in[8];
    const float* b2   = (const float*)d_in[9];

    const int N = in_sizes[0] / IN_C;
    const int E = in_sizes[1] / 2;
    const int* src = ei;
    const int* dst = ei + E;

    // workspace layout (all f16 feature buffers)
    float* ws = (float*)d_ws;
    size_t o = 0;
    _Float16* xlh = (_Float16*)(ws + o); o += (size_t)N * IN_C / 2;  // x@Wl / h@W2l
    _Float16* xrh = (_Float16*)(ws + o); o += (size_t)N * IN_C / 2;  // x@Wr / h@W2r
    _Float16* hb  = (_Float16*)(ws + o); o += (size_t)N * IN_C / 2;  // layer1 out (post-ELU)
    int* iws    = (int*)(ws + o);
    int* rowptr = iws;                    // N+1
    int* cnt    = iws + (N + 1);          // N
    int* cursor = iws + (N + 1) + N;      // N   (seeded by scan_final)
    int* part   = iws + (N + 1) + 2 * N;  // <=1024 block partials
    ushort_t* gsrc = (ushort_t*)(iws + (N + 1) + 2 * N + 1024);  // E (CSR src ids)

    hipMemsetAsync(cnt, 0, (size_t)N * 4, stream);

    const int B = 256;
    const int nb = (N + 255) / 256;
    // ---- CSR by dst (shared by both layers) ----
    hist_kernel<<<(E + B - 1) / B, B, 0, stream>>>(dst, cnt, E);
    scan_block_sums<<<nb, 256, 0, stream>>>(cnt, part, N);
    scan_part_excl<<<1, 1024, 0, stream>>>(part, nb);
    scan_final<<<nb, 256, 0, stream>>>(cnt, part, rowptr, cursor, N);
    scatter_csr<<<(E + B - 1) / B, B, 0, stream>>>(src, dst, cursor, gsrc, E);

    // ---- layer 1 ----
    transform_mfma<false><<<512, 256, 0, stream>>>(x, W1l, W1r, xlh, xrh, N);
    node_fused1<<<(N + 3) / 4, 256, 0, stream>>>(xlh, xrh, att1, rowptr, gsrc, b1, hb, N);

    // ---- layer 2 ----
    transform_mfma<true><<<512, 256, 0, stream>>>(hb, W2l, W2r, xlh, xrh, N);
    node_fused2<<<(N + 3) / 4, 256, 0, stream>>>(xlh, xrh, att2, rowptr, gsrc, b2, (float*)d_out, N);
}

// Round 5
// 283.331 us; speedup vs baseline: 1.4471x; 1.0672x over previous
//
#include <hip/hip_runtime.h>
#include <math.h>

#define IN_C 128
#define NEG_SLOPE 0.2f
#define LOG2E 1.44269504f

typedef unsigned int uint_t;
typedef unsigned short ushort_t;
typedef _Float16 half8_t __attribute__((ext_vector_type(8)));
typedef _Float16 half2_t __attribute__((ext_vector_type(2)));
typedef float floatx4 __attribute__((ext_vector_type(4)));

// f16 pair dot with f32 accumulate (v_dot2_f32_f16); safe fallback
__device__ __forceinline__ float fdot2f(half2_t a, half2_t b, float c) {
#if __has_builtin(__builtin_amdgcn_fdot2)
    return __builtin_amdgcn_fdot2(a, b, c, false);
#else
    return fmaf((float)a[1], (float)b[1], fmaf((float)a[0], (float)b[0], c));
#endif
}
#define H2(v, i) ((half2_t){(v)[2 * (i)], (v)[2 * (i) + 1]})

__device__ __forceinline__ float fexp2(float x) {
#if __has_builtin(__builtin_amdgcn_exp2f)
    return __builtin_amdgcn_exp2f(x);
#else
    return exp2f(x);
#endif
}

// single-instruction cross-lane add via DPP (quad_perm / row mirrors)
template <int CTRL>
__device__ __forceinline__ float dpp_addf(float x) {
    int y = __builtin_amdgcn_update_dpp(0, __float_as_int(x), CTRL, 0xF, 0xF, true);
    return x + __int_as_float(y);
}

// ---------- MFMA dual transform: outl = x@Wl (f16), outr = x@Wr (f16) ----------
#define XPAD 136
template <bool IN_HALF>
__global__ __launch_bounds__(256) void transform_mfma(
        const void* __restrict__ xin,
        const float* __restrict__ Wl,
        const float* __restrict__ Wr,
        _Float16* __restrict__ outl,
        _Float16* __restrict__ outr, int n) {
    __shared__ _Float16 xs[16 * XPAD + 8];
    const int tid  = threadIdx.x;
    const int wv   = tid >> 6;
    const int l    = tid & 63;
    const int lm   = l & 15;
    const int quad = l >> 4;
    const int kb   = quad * 8;

    const float* Wsel = (wv < 2) ? Wl : Wr;
    _Float16*    osel = (wv < 2) ? outl : outr;
    const int nbase = (wv & 1) * 64;
    half8_t bw[4][4];
#pragma unroll
    for (int t = 0; t < 4; ++t) {
        const int ncol = nbase + t * 16 + lm;
#pragma unroll
        for (int K = 0; K < 4; ++K) {
            const int k0 = K * 32 + kb;
            half8_t h;
#pragma unroll
            for (int j = 0; j < 8; ++j)
                h[j] = (_Float16)Wsel[(size_t)(k0 + j) * IN_C + ncol];
            bw[t][K] = h;
        }
    }

    const int nStrips = (n + 15) >> 4;
    for (int s = blockIdx.x; s < nStrips; s += gridDim.x) {
        const int row0 = s * 16;
        __syncthreads();
        {
            const int srow = tid >> 4;
            const int scol = (tid & 15) * 8;
            const int grow = row0 + srow;
            half8_t h;
#pragma unroll
            for (int j = 0; j < 8; ++j) h[j] = (_Float16)0.f;
            if (grow < n) {
                if constexpr (IN_HALF) {
                    h = *(const half8_t*)&((const _Float16*)xin)[(size_t)grow * IN_C + scol];
                } else {
                    const float4 v0 = *(const float4*)&((const float*)xin)[(size_t)grow * IN_C + scol];
                    const float4 v1 = *(const float4*)&((const float*)xin)[(size_t)grow * IN_C + scol + 4];
                    h[0] = (_Float16)v0.x; h[1] = (_Float16)v0.y;
                    h[2] = (_Float16)v0.z; h[3] = (_Float16)v0.w;
                    h[4] = (_Float16)v1.x; h[5] = (_Float16)v1.y;
                    h[6] = (_Float16)v1.z; h[7] = (_Float16)v1.w;
                }
            }
            *(half8_t*)&xs[srow * XPAD + scol] = h;
        }
        __syncthreads();
        half8_t af[4];
#pragma unroll
        for (int K = 0; K < 4; ++K)
            af[K] = *(half8_t*)&xs[lm * XPAD + K * 32 + kb];
        floatx4 acc[4];
#pragma unroll
        for (int t = 0; t < 4; ++t) acc[t] = (floatx4){0.f, 0.f, 0.f, 0.f};
#pragma unroll
        for (int t = 0; t < 4; ++t)
#pragma unroll
            for (int K = 0; K < 4; ++K)
                acc[t] = __builtin_amdgcn_mfma_f32_16x16x32_f16(af[K], bw[t][K], acc[t], 0, 0, 0);
#pragma unroll
        for (int t = 0; t < 4; ++t) {
            const int col = nbase + t * 16 + lm;
#pragma unroll
            for (int r = 0; r < 4; ++r) {
                const int row = row0 + quad * 4 + r;
                if (row < n) osel[(size_t)row * IN_C + col] = (_Float16)acc[t][r];
            }
        }
    }
}

// ---------- CSR build (rows padded to multiples of 4 slots) ----------
__global__ void hist_kernel(const int* __restrict__ dst, int* __restrict__ cnt, int E) {
    int e = blockIdx.x * blockDim.x + threadIdx.x;
    if (e < E) atomicAdd(&cnt[dst[e]], 1);
}

__global__ void scan_block_sums(const int* __restrict__ cnt, int* __restrict__ part, int n) {
    __shared__ int sdata[256];
    int t = threadIdx.x;
    int i = blockIdx.x * 256 + t;
    sdata[t] = (i < n) ? ((cnt[i] + 3) & ~3) : 0;   // padded counts
    __syncthreads();
    for (int o = 128; o >= 1; o >>= 1) {
        if (t < o) sdata[t] += sdata[t + o];
        __syncthreads();
    }
    if (t == 0) part[blockIdx.x] = sdata[0];
}

__global__ void scan_part_excl(int* __restrict__ part, int nb) {  // single block
    __shared__ int buf[1024];
    int t = threadIdx.x;
    int v = (t < nb) ? part[t] : 0;
    buf[t] = v;
    __syncthreads();
    for (int o = 1; o < 1024; o <<= 1) {
        int a = (t >= o) ? buf[t - o] : 0;
        __syncthreads();
        buf[t] += a;
        __syncthreads();
    }
    if (t < nb) part[t] = buf[t] - v;   // exclusive
}

__global__ void scan_final(const int* __restrict__ cnt, const int* __restrict__ part,
                           int* __restrict__ rowptr, int* __restrict__ cursor, int n) {
    __shared__ int buf[256];
    int t = threadIdx.x;
    int i = blockIdx.x * 256 + t;
    int v = (i < n) ? ((cnt[i] + 3) & ~3) : 0;      // padded counts
    buf[t] = v;
    __syncthreads();
    for (int o = 1; o < 256; o <<= 1) {
        int a = (t >= o) ? buf[t - o] : 0;
        __syncthreads();
        buf[t] += a;
        __syncthreads();
    }
    int excl = part[blockIdx.x] + buf[t] - v;
    if (i < n) { rowptr[i] = excl; cursor[i] = excl; }
    if (i == n - 1) rowptr[n] = excl + v;
}

__global__ void scatter_csr(const int* __restrict__ src,
                            const int* __restrict__ dst,
                            int* __restrict__ cursor,
                            ushort_t* __restrict__ gsrc, int E) {
    int e = blockIdx.x * blockDim.x + threadIdx.x;
    if (e >= E) return;
    int pos = atomicAdd(&cursor[dst[e]], 1);
    gsrc[pos] = (ushort_t)src[e];
}

// ---------- fused node kernel: 4 dsts per wave, 16 lanes per dst ----------
// lane = (s, q): s = dst slot (0..3), q = channel lane (0..15, 8 ch each).
// Per tile: 4 edges per dst from ONE aligned 8B gsrc load (rows 4-padded).
// Score reduce entirely within the 16-lane DPP row (no ds_bpermute):
//   L1 (head = q>>2, 32ch): quad_perm 0xB1 + 0x4E
//   L2 (128ch):             + row_half_mirror 0x141 + row_mirror 0x140
// Softmax state (m, ls) per-lane; log2 domain (att pre-scaled by log2e);
// defer-max rescale; pad slots read gsrc=0 (memset) -> finite data, wgt=0.
template <int LAYER>   // 1: 4 heads + ELU + f16 out; 2: 1 head, f32 out
__global__ __launch_bounds__(256) void node_fused(
        const _Float16* __restrict__ xlb,
        const _Float16* __restrict__ xr,
        const float* __restrict__ att,
        const int* __restrict__ rowptr,
        const int* __restrict__ cnt,
        const ushort_t* __restrict__ gsrc,
        const float* __restrict__ bias,
        void* __restrict__ outp, int N) {
    const int l = threadIdx.x & 63;
    const int q = l & 15;
    const int d = blockIdx.x * 16 + (threadIdx.x >> 4);
    if (d >= N) return;
    const int beg = rowptr[d];
    const int deg = cnt[d];
    const int nt  = (deg + 3) >> 2;
    const int cb  = q * 8;

    const half8_t xrv = *(const half8_t*)&xr[(size_t)d * IN_C + cb];
    const float4 A0 = *(const float4*)&att[cb];
    const float4 A1 = *(const float4*)&att[cb + 4];
    const float afv[8] = {A0.x, A0.y, A0.z, A0.w, A1.x, A1.y, A1.z, A1.w};
    half8_t a6, a4;
#pragma unroll
    for (int j = 0; j < 8; ++j) {
        a6[j] = (_Float16)(0.6f * LOG2E * afv[j]);
        a4[j] = (_Float16)(0.4f * LOG2E * afv[j]);
    }

    float m = -1e30f, ls = 0.f;
    float acc[8] = {0.f, 0.f, 0.f, 0.f, 0.f, 0.f, 0.f, 0.f};

    const uint2* gp = (const uint2*)(gsrc + beg);   // beg % 4 == 0 -> 8B aligned
    uint2 gcur;
    half8_t xc[4];
    if (nt > 0) {
        gcur = gp[0];
        uint_t i0 = gcur.x & 0xffffu, i1 = gcur.x >> 16;
        uint_t i2 = gcur.y & 0xffffu, i3 = gcur.y >> 16;
        xc[0] = *(const half8_t*)(xlb + (i0 << 7) + cb);
        xc[1] = *(const half8_t*)(xlb + (i1 << 7) + cb);
        xc[2] = *(const half8_t*)(xlb + (i2 << 7) + cb);
        xc[3] = *(const half8_t*)(xlb + (i3 << 7) + cb);
    }

    for (int t = 0; t < nt; ++t) {
        // prefetch next tile's indices (clamped to last tile)
        const int tn = (t + 1 < nt) ? t + 1 : t;
        uint2 gnext = gp[tn];
        // scores (log2 domain) on current tile
        float f[4];
#pragma unroll
        for (int u = 0; u < 4; ++u) {
            half8_t tv = xc[u] + xrv;                 // 4x v_pk_add_f16
            uint4 tu = __builtin_bit_cast(uint4, tv);
            tu.x &= 0x7fff7fffu; tu.y &= 0x7fff7fffu;
            tu.z &= 0x7fff7fffu; tu.w &= 0x7fff7fffu; // |t| packed
            half8_t av = __builtin_bit_cast(half8_t, tu);
            float p = 0.f;
#pragma unroll
            for (int j = 0; j < 4; ++j) p = fdot2f(H2(tv, j), H2(a6, j), p);
#pragma unroll
            for (int j = 0; j < 4; ++j) p = fdot2f(H2(av, j), H2(a4, j), p);
            p = dpp_addf<0xB1>(p);                    // + lane^1
            p = dpp_addf<0x4E>(p);                    // + lane^2
            if (LAYER == 2) {
                p = dpp_addf<0x141>(p);               // + across quads (half row)
                p = dpp_addf<0x140>(p);               // + across half-rows
            }
            f[u] = (4 * t + u < deg) ? p : -1e30f;
        }
        float bm = fmaxf(fmaxf(f[0], f[1]), fmaxf(f[2], f[3]));
        if (!__all(bm <= m + 5.7708f)) {              // rescale (incl. first tile)
            float nm = fmaxf(m, bm);
            float fc = fexp2(m - nm);
            ls *= fc;
#pragma unroll
            for (int j = 0; j < 8; ++j) acc[j] *= fc;
            m = nm;
        }
        // issue next tile's gathers before the accumulation phase
        half8_t xn[4];
        {
            uint_t i0 = gnext.x & 0xffffu, i1 = gnext.x >> 16;
            uint_t i2 = gnext.y & 0xffffu, i3 = gnext.y >> 16;
            xn[0] = *(const half8_t*)(xlb + (i0 << 7) + cb);
            xn[1] = *(const half8_t*)(xlb + (i1 << 7) + cb);
            xn[2] = *(const half8_t*)(xlb + (i2 << 7) + cb);
            xn[3] = *(const half8_t*)(xlb + (i3 << 7) + cb);
        }
        // accumulate current tile
#pragma unroll
        for (int u = 0; u < 4; ++u) {
            float wgt = fexp2(f[u] - m);
            ls += wgt;
#pragma unroll
            for (int j = 0; j < 8; ++j)               // v_fma_mix: f16*f32+f32
                acc[j] = fmaf((float)xc[u][j], wgt, acc[j]);
        }
#pragma unroll
        for (int u = 0; u < 4; ++u) xc[u] = xn[u];
        gcur = gnext;
    }

    // epilogue: all 16 lanes write their dst's 8 channels
    const float inv = (ls > 0.f) ? 1.f / ls : 0.f;
    const float4 b0 = *(const float4*)&bias[cb];
    const float4 b1 = *(const float4*)&bias[cb + 4];
    const float bf[8] = {b0.x, b0.y, b0.z, b0.w, b1.x, b1.y, b1.z, b1.w};
    if (LAYER == 1) {
        half8_t h;
#pragma unroll
        for (int j = 0; j < 8; ++j) {
            float o = acc[j] * inv + bf[j];
            o = (o > 0.f) ? o : fexp2(o * LOG2E) - 1.f;   // ELU
            h[j] = (_Float16)o;
        }
        *(half8_t*)&((_Float16*)outp)[(size_t)d * IN_C + cb] = h;
    } else {
        float4 o1, o2;
        o1.x = acc[0] * inv + bf[0]; o1.y = acc[1] * inv + bf[1];
        o1.z = acc[2] * inv + bf[2]; o1.w = acc[3] * inv + bf[3];
        o2.x = acc[4] * inv + bf[4]; o2.y = acc[5] * inv + bf[5];
        o2.z = acc[6] * inv + bf[6]; o2.w = acc[7] * inv + bf[7];
        *(float4*)&((float*)outp)[(size_t)d * IN_C + cb]     = o1;
        *(float4*)&((float*)outp)[(size_t)d * IN_C + cb + 4] = o2;
    }
}

extern "C" void kernel_launch(void* const* d_in, const int* in_sizes, int n_in,
                              void* d_out, int out_size, void* d_ws, size_t ws_size,
                              hipStream_t stream) {
    const float* x    = (const float*)d_in[0];
    const int*   ei   = (const int*)d_in[1];
    const float* W1l  = (const float*)d_in[2];
    const float* W1r  = (const float*)d_in[3];
    const float* att1 = (const float*)d_in[4];
    const float* b1   = (const float*)d_in[5];
    const float* W2l  = (const float*)d_in[6];
    const float* W2r  = (const float*)d_in[7];
    const float* att2 = (const float*)d_in[8];
    const float* b2   = (const float*)d_in[9];

    const int N = in_sizes[0] / IN_C;
    const int E = in_sizes[1] / 2;
    const int* src = ei;
    const int* dst = ei + E;

    // workspace layout (all f16 feature buffers)
    float* ws = (float*)d_ws;
    size_t o = 0;
    _Float16* xlh = (_Float16*)(ws + o); o += (size_t)N * IN_C / 2;  // x@Wl / h@W2l
    _Float16* xrh = (_Float16*)(ws + o); o += (size_t)N * IN_C / 2;  // x@Wr / h@W2r
    _Float16* hb  = (_Float16*)(ws + o); o += (size_t)N * IN_C / 2;  // layer1 out (post-ELU)
    int* iws    = (int*)(ws + o);
    int* rowptr = iws;                    // N+1 (padded row starts, x4-aligned)
    int* cnt    = iws + (N + 1);          // N   (true degrees)
    int* cursor = iws + (N + 1) + N;      // N   (seeded by scan_final)
    int* part   = iws + (N + 1) + 2 * N;  // <=1024 block partials
    ushort_t* gsrc = (ushort_t*)(iws + (N + 1) + 2 * N + 1024);  // E + 4N pad slots
    const size_t gsrc_bytes = ((size_t)E + 4 * (size_t)N + 64) * sizeof(ushort_t);

    hipMemsetAsync(cnt, 0, (size_t)N * 4, stream);
    hipMemsetAsync(gsrc, 0, gsrc_bytes, stream);   // pad slots -> node 0 (finite)

    const int B = 256;
    const int nb = (N + 255) / 256;
    // ---- CSR by dst, rows padded to x4 (shared by both layers) ----
    hist_kernel<<<(E + B - 1) / B, B, 0, stream>>>(dst, cnt, E);
    scan_block_sums<<<nb, 256, 0, stream>>>(cnt, part, N);
    scan_part_excl<<<1, 1024, 0, stream>>>(part, nb);
    scan_final<<<nb, 256, 0, stream>>>(cnt, part, rowptr, cursor, N);
    scatter_csr<<<(E + B - 1) / B, B, 0, stream>>>(src, dst, cursor, gsrc, E);

    // ---- layer 1 ----
    transform_mfma<false><<<512, 256, 0, stream>>>(x, W1l, W1r, xlh, xrh, N);
    node_fused<1><<<(N + 15) / 16, 256, 0, stream>>>(xlh, xrh, att1, rowptr, cnt, gsrc, b1, hb, N);

    // ---- layer 2 ----
    transform_mfma<true><<<512, 256, 0, stream>>>(hb, W2l, W2r, xlh, xrh, N);
    node_fused<2><<<(N + 15) / 16, 256, 0, stream>>>(xlh, xrh, att2, rowptr, cnt, gsrc, b2, d_out, N);
}